// Round 9
// baseline (409.266 us; speedup 1.0000x reference)
//
#include <hip/hip_runtime.h>
#include <hip/hip_bf16.h>
#include <math.h>

#define Mdim 2048
#define FD   128

typedef __attribute__((ext_vector_type(8))) short short8;
typedef __attribute__((ext_vector_type(4))) float f32x4;

// ---------- pack float -> monotone u32 key | 11-bit global col index ----------
__device__ __forceinline__ unsigned pkey(float v, int n) {
    unsigned u = __float_as_uint(v);
    unsigned mk = u ^ ((unsigned)((int)u >> 31) | 0x80000000u);
    return (mk & 0xFFFFF800u) | (unsigned)n;
}

// branchless sorted-desc top-3 insert on packed keys
__device__ __forceinline__ void ins3p(unsigned k, unsigned t[3]) {
    bool g2 = k > t[2], g1 = k > t[1], g0 = k > t[0];
    t[2] = g1 ? t[1] : (g2 ? k : t[2]);
    t[1] = g0 ? t[0] : (g1 ? k : t[1]);
    t[0] = g0 ? k : t[0];
}

// sorted-desc top-8 insert with early-out (packed keys)
__device__ __forceinline__ void ins8p(unsigned k, unsigned bv[8]) {
    if (k <= bv[7]) return;
    #pragma unroll
    for (int s = 0; s < 8; ++s) {
        if (k > bv[s]) { unsigned o = bv[s]; bv[s] = k; k = o; }
    }
}

// ---------- Kernel 0: streaming zero of the output (isolated, textbook) ----------
__global__ void zero_kernel(float4* __restrict__ out, int n4) {
    int idx = blockIdx.x * 256 + threadIdx.x;
    int stride = gridDim.x * 256;
    float4 z = make_float4(0.f, 0.f, 0.f, 0.f);
    for (int i = idx; i < n4; i += stride) out[i] = z;
}

// ---------- Kernel 1: fp64 norms + normalized bf16 copy ----------
__global__ void prep_kernel(const float* __restrict__ x,
                            double* __restrict__ nrm_d,
                            unsigned short* __restrict__ xnb) {
    __shared__ unsigned short sb[4][128];
    int w = threadIdx.x >> 6, lane = threadIdx.x & 63;
    int row = blockIdx.x * 4 + w;
    const float* p = x + (size_t)row * FD;
    float v0 = p[lane], v1 = p[lane + 64];
    double d = (double)v0 * (double)v0 + (double)v1 * (double)v1;
    #pragma unroll
    for (int off = 32; off; off >>= 1) d += __shfl_down(d, off);
    d = __shfl(d, 0);
    double nrm = fmax(sqrt(d), 1e-12);
    if (lane == 0) nrm_d[row] = nrm;
    double inv = 1.0 / nrm;
    __hip_bfloat16 ha = __float2bfloat16((float)((double)v0 * inv));
    __hip_bfloat16 hb = __float2bfloat16((float)((double)v1 * inv));
    sb[w][lane]      = *reinterpret_cast<unsigned short*>(&ha);
    sb[w][lane + 64] = *reinterpret_cast<unsigned short*>(&hb);
    __syncthreads();
    if (lane < 16) {
        short8 v = *(const short8*)&sb[w][lane * 8];
        *(short8*)(xnb + (size_t)row * FD + lane * 8) = v;
    }
}

// ---------- Kernel 2: XCD-local gather GEMM + top-8 pools (no output writes) ----------
// 1024 blocks x 4 waves. blockIdx%8 -> XCD (round-robin): each XCD serves only
// batches {2x, 2x+1} => per-XCD B working set = 1 MB, L2-resident.
// Wave = 32 rows x 512-col segment (seg = wave id). B frags double-buffered.
__launch_bounds__(256, 3)
__global__ void gemm_kernel(const unsigned short* __restrict__ xnb,
                            unsigned* __restrict__ pools) {
    __shared__ unsigned mbuf[4][32 * 49];

    int tid  = threadIdx.x;
    int lane = tid & 63;
    int w    = tid >> 6;
    int x8   = blockIdx.x & 7;             // XCD (assumed blockIdx%8 round-robin)
    int j    = blockIdx.x >> 3;            // 0..127
    int b    = x8 * 2 + (j & 1);           // 2 batches per XCD
    int rt   = j >> 1;                     // 0..63 row-tiles of 32
    int row0 = rt * 32;
    int cb   = w * 512;                    // wave w owns column segment w
    const unsigned short* xb = xnb + (size_t)b * Mdim * FD;

    int c = lane & 15, q = lane >> 4;

    // A fragments: rows row0 + rs*16 + c, k = s*32 + q*8
    short8 afr[2][4];
    #pragma unroll
    for (int rs = 0; rs < 2; ++rs)
        #pragma unroll
        for (int s = 0; s < 4; ++s)
            afr[rs][s] = *(const short8*)(xb + (size_t)(row0 + rs*16 + c) * FD + s*32 + q*8);

    unsigned tvp[8][3];
    #pragma unroll
    for (int i = 0; i < 8; ++i) { tvp[i][0] = 0; tvp[i][1] = 0; tvp[i][2] = 0; }

    // B fragment double buffer: loads for step s+1 fly during MFMAs of step s
    short8 bcur[4], bnxt[4];
    #pragma unroll
    for (int ct = 0; ct < 4; ++ct)
        bcur[ct] = *(const short8*)(xb + (size_t)(cb + ct*16 + c) * FD + q*8);

    #pragma unroll 1
    for (int ch = 0; ch < 8; ++ch) {
        int col0 = cb + ch * 64;

        f32x4 acc[2][4];
        #pragma unroll
        for (int rs = 0; rs < 2; ++rs)
            #pragma unroll
            for (int ct = 0; ct < 4; ++ct)
                acc[rs][ct] = (f32x4){0.f, 0.f, 0.f, 0.f};

        #pragma unroll
        for (int s = 0; s < 4; ++s) {
            // prefetch next k-step (or next chunk's s=0)
            int nch  = (s == 3) ? ch + 1 : ch;
            int ns   = (s == 3) ? 0 : s + 1;
            if (nch < 8) {
                int ncol = cb + nch * 64;
                #pragma unroll
                for (int ct = 0; ct < 4; ++ct)
                    bnxt[ct] = *(const short8*)(xb + (size_t)(ncol + ct*16 + c) * FD + ns*32 + q*8);
            }
            #pragma unroll
            for (int ct = 0; ct < 4; ++ct) {
                acc[0][ct] = __builtin_amdgcn_mfma_f32_16x16x32_bf16(afr[0][s], bcur[ct], acc[0][ct], 0, 0, 0);
                acc[1][ct] = __builtin_amdgcn_mfma_f32_16x16x32_bf16(afr[1][s], bcur[ct], acc[1][ct], 0, 0, 0);
            }
            #pragma unroll
            for (int ct = 0; ct < 4; ++ct) bcur[ct] = bnxt[ct];
        }

        // scan on packed keys (diag competes; dropped at final select)
        int nbase = col0 + c;
        #pragma unroll
        for (int rs = 0; rs < 2; ++rs)
            #pragma unroll
            for (int i = 0; i < 4; ++i) {
                int rr = rs*4 + i;
                unsigned k0 = pkey(acc[rs][0][i], nbase);
                unsigned k1 = pkey(acc[rs][1][i], nbase + 16);
                unsigned k2 = pkey(acc[rs][2][i], nbase + 32);
                unsigned k3 = pkey(acc[rs][3][i], nbase + 48);
                unsigned mx = max(max(k0, k1), max(k2, k3));
                if (mx > tvp[rr][2]) {
                    ins3p(k0, tvp[rr]);
                    ins3p(k1, tvp[rr]);
                    ins3p(k2, tvp[rr]);
                    ins3p(k3, tvp[rr]);
                }
            }
    }

    // ---- cross-lane merge via per-wave LDS scratch ----
    unsigned* mb = mbuf[w];
    #pragma unroll
    for (int rs = 0; rs < 2; ++rs)
        #pragma unroll
        for (int i = 0; i < 4; ++i) {
            int r = rs*16 + q*4 + i;
            #pragma unroll
            for (int j2 = 0; j2 < 3; ++j2)
                mb[r*49 + c*3 + j2] = tvp[rs*4 + i][j2];
        }
    __syncthreads();
    if (lane < 32) {
        unsigned bv[8];
        #pragma unroll
        for (int s = 0; s < 8; ++s) bv[s] = 0;
        for (int s2 = 0; s2 < 48; ++s2)
            ins8p(mb[lane*49 + s2], bv);
        unsigned* pp = pools + ((size_t)b * Mdim + row0 + lane) * 32 + w * 8;
        #pragma unroll
        for (int s = 0; s < 8; ++s) pp[s] = bv[s];
    }
}

// ---------- Kernel 3: merge segments + fp64 refine + exact top-2 + atomic scatter ----------
__global__ void select_kernel(const float* __restrict__ x,
                              const double* __restrict__ nrm_d,
                              const unsigned* __restrict__ pools,
                              float* __restrict__ out) {
    __shared__ unsigned keys[32][8];
    __shared__ double   fval[32][9];
    int tid = threadIdx.x;
    int r = tid >> 3, s = tid & 7;
    int rowg = blockIdx.x * 32 + r;
    int b = rowg >> 11, m = rowg & (Mdim - 1);

    if (s == 0) {
        unsigned bv[8];
        #pragma unroll
        for (int i = 0; i < 8; ++i) bv[i] = 0;
        const unsigned* pp = pools + (size_t)rowg * 32;
        #pragma unroll
        for (int i = 0; i < 32; ++i) ins8p(pp[i], bv);
        #pragma unroll
        for (int i = 0; i < 8; ++i) keys[r][i] = bv[i];
    }
    __syncthreads();

    {
        int n = (int)(keys[r][s] & 2047u);
        const float* xf = x + (size_t)b * Mdim * FD;
        const double* nb = nrm_d + (size_t)b * Mdim;
        const f32x4* pm = (const f32x4*)(xf + (size_t)m * FD);
        const f32x4* pn = (const f32x4*)(xf + (size_t)n * FD);
        double a0 = 0.0, a1 = 0.0;
        #pragma unroll 4
        for (int k4 = 0; k4 < FD/4; k4 += 2) {
            f32x4 u0 = pm[k4],   vv0 = pn[k4];
            f32x4 u1 = pm[k4+1], vv1 = pn[k4+1];
            a0 = fma((double)u0[0], (double)vv0[0], a0);
            a0 = fma((double)u0[1], (double)vv0[1], a0);
            a0 = fma((double)u0[2], (double)vv0[2], a0);
            a0 = fma((double)u0[3], (double)vv0[3], a0);
            a1 = fma((double)u1[0], (double)vv1[0], a1);
            a1 = fma((double)u1[1], (double)vv1[1], a1);
            a1 = fma((double)u1[2], (double)vv1[2], a1);
            a1 = fma((double)u1[3], (double)vv1[3], a1);
        }
        fval[r][s] = (a0 + a1) / (nb[m] * nb[n]);
    }
    __syncthreads();

    if (s == 0) {
        double bv1 = -1e300, bv2 = -1e300; int bi1 = -1, bi2 = -1;
        #pragma unroll
        for (int cc = 0; cc < 8; ++cc) {
            double v = fval[r][cc];
            int    n = (int)(keys[r][cc] & 2047u);
            if (n == m) continue;           // drop self-similarity (diag)
            if (bi1 < 0 || v > bv1 || (v == bv1 && n < bi1)) {
                bv2 = bv1; bi2 = bi1; bv1 = v; bi1 = n;
            } else if (bi2 < 0 || v > bv2 || (v == bv2 && n < bi2)) {
                bv2 = v; bi2 = n;
            }
        }
        float* ob = out + (size_t)b * Mdim * Mdim;
        // reference top_k competes against the zeroed diagonal (value 0):
        // val1 always scatters; val2 only if it beats the diagonal zero.
        float h1 = (float)(0.5 * bv1);
        atomicAdd(ob + (size_t)m * Mdim + bi1, h1);
        atomicAdd(ob + (size_t)bi1 * Mdim + m, h1);
        if (bv2 > 0.0) {
            float h2 = (float)(0.5 * bv2);
            atomicAdd(ob + (size_t)m * Mdim + bi2, h2);
            atomicAdd(ob + (size_t)bi2 * Mdim + m, h2);
        }
    }
}

extern "C" void kernel_launch(void* const* d_in, const int* in_sizes, int n_in,
                              void* d_out, int out_size, void* d_ws, size_t ws_size,
                              hipStream_t stream) {
    const float* x = (const float*)d_in[0];
    float* out = (float*)d_out;
    int Bn = in_sizes[0] / (Mdim * FD);   // 16

    char* ws = (char*)d_ws;
    double*         nrm_d = (double*)ws;                          // 256 KB
    unsigned short* xnb   = (unsigned short*)(ws + 262144);       // 8 MB
    unsigned*       pools = (unsigned*)(ws + 262144 + 8388608);   // 4 MB

    zero_kernel<<<4096, 256, 0, stream>>>((float4*)out, out_size / 4);
    prep_kernel<<<Bn * Mdim / 4, 256, 0, stream>>>(x, nrm_d, xnb);
    gemm_kernel<<<Bn * 64, 256, 0, stream>>>(xnb, pools);          // 1024 blocks
    select_kernel<<<Bn * Mdim / 32, 256, 0, stream>>>(x, nrm_d, pools, out);
}

// Round 10
// 343.510 us; speedup vs baseline: 1.1914x; 1.1914x over previous
//
#include <hip/hip_runtime.h>
#include <hip/hip_bf16.h>
#include <math.h>

#define Mdim 2048
#define FD   128

typedef __attribute__((ext_vector_type(8))) short short8;
typedef __attribute__((ext_vector_type(4))) float f32x4;

// ---------- pack float -> monotone u32 key | 11-bit global col index ----------
__device__ __forceinline__ unsigned pkey(float v, int n) {
    unsigned u = __float_as_uint(v);
    unsigned mk = u ^ ((unsigned)((int)u >> 31) | 0x80000000u);
    return (mk & 0xFFFFF800u) | (unsigned)n;
}

// branchless sorted-desc top-3 insert on packed keys
__device__ __forceinline__ void ins3p(unsigned k, unsigned t[3]) {
    bool g2 = k > t[2], g1 = k > t[1], g0 = k > t[0];
    t[2] = g1 ? t[1] : (g2 ? k : t[2]);
    t[1] = g0 ? t[0] : (g1 ? k : t[1]);
    t[0] = g0 ? k : t[0];
}

// sorted-desc top-8 insert with early-out (packed keys)
__device__ __forceinline__ void ins8p(unsigned k, unsigned bv[8]) {
    if (k <= bv[7]) return;
    #pragma unroll
    for (int s = 0; s < 8; ++s) {
        if (k > bv[s]) { unsigned o = bv[s]; bv[s] = k; k = o; }
    }
}

// ---------- Kernel 1: fp64 norms + normalized bf16 copy, chunk-swizzled ----------
// xnb row r, physical 16B-chunk p holds logical chunk j = p ^ (r & 15).
__global__ void prep_kernel(const float* __restrict__ x,
                            double* __restrict__ nrm_d,
                            unsigned short* __restrict__ xnb) {
    __shared__ unsigned short sb[4][128];
    int w = threadIdx.x >> 6, lane = threadIdx.x & 63;
    int row = blockIdx.x * 4 + w;
    const float* p = x + (size_t)row * FD;
    float v0 = p[lane], v1 = p[lane + 64];
    double d = (double)v0 * (double)v0 + (double)v1 * (double)v1;
    #pragma unroll
    for (int off = 32; off; off >>= 1) d += __shfl_down(d, off);
    d = __shfl(d, 0);
    double nrm = fmax(sqrt(d), 1e-12);
    if (lane == 0) nrm_d[row] = nrm;
    double inv = 1.0 / nrm;
    __hip_bfloat16 ha = __float2bfloat16((float)((double)v0 * inv));
    __hip_bfloat16 hb = __float2bfloat16((float)((double)v1 * inv));
    sb[w][lane]      = *reinterpret_cast<unsigned short*>(&ha);
    sb[w][lane + 64] = *reinterpret_cast<unsigned short*>(&hb);
    __syncthreads();
    if (lane < 16) {
        int j = lane ^ (row & 15);   // logical chunk stored at physical 'lane'
        short8 v = *(const short8*)&sb[w][j * 8];
        *(short8*)(xnb + (size_t)row * FD + lane * 8) = v;
    }
}

// ---------- Kernel 2: 128-row x 1024-col GEMM, double-buffered DMA ----------
// 512 blocks (16 batches x 16 row-tiles x 2 col-halves). 4 waves; wave w owns
// rows [row0+w*32, +32). 16 chunks of 64 cols, LDS buffers ping-pong; DMA for
// chunk ch+1 issues AFTER the barrier so the barrier never drains a fresh load.
__launch_bounds__(256, 2)
__global__ void gemm_kernel(const unsigned short* __restrict__ xnb,
                            unsigned* __restrict__ pools,
                            float* __restrict__ out) {
    // LDS: two 16-KB B buffers [64 cols][128 k]; merge scratch reuses buf0/1.
    __shared__ __align__(16) unsigned short Bbuf[2][64 * 128];

    int blk = blockIdx.x;
    int b   = blk >> 5;                 // 32 blocks per batch
    int rt  = (blk >> 1) & 15;          // 16 row-tiles of 128
    int hf  = blk & 1;                  // 2 column halves of 1024
    int row0 = rt * 128;
    int cb   = hf * 1024;
    const unsigned short* xb = xnb + (size_t)b * Mdim * FD;

    int tid  = threadIdx.x;
    int lane = tid & 63;
    int w    = tid >> 6;
    int c    = lane & 15, q = lane >> 4;

    // A fragments: rows row0 + w*32 + rs*16 + c (row&15 == c -> swizzle key c)
    short8 afr[2][4];
    #pragma unroll
    for (int rs = 0; rs < 2; ++rs)
        #pragma unroll
        for (int s = 0; s < 4; ++s) {
            int p = ((s << 2) + q) ^ c;
            afr[rs][s] = *(const short8*)(xb + (size_t)(row0 + w*32 + rs*16 + c) * FD + p * 8);
        }

    unsigned tvp[8][3];
    #pragma unroll
    for (int i = 0; i < 8; ++i) { tvp[i][0] = 0; tvp[i][1] = 0; tvp[i][2] = 0; }

    // DMA helper pattern: wave w stages 16 cols (4 issues x 4 cols) per chunk
    // lane l -> col (base + i*4 + (l>>4)), physical k-chunk (l&15)
    // prologue: chunk 0 -> buf 0
    {
        int col0 = cb;
        #pragma unroll
        for (int i = 0; i < 4; ++i) {
            const void* gp = xb + (size_t)(col0 + w*16 + i*4 + (lane >> 4)) * FD + (lane & 15) * 8;
            void* lp = (char*)&Bbuf[0][(w*16 + i*4) * 128];
            __builtin_amdgcn_global_load_lds(
                (const __attribute__((address_space(1))) unsigned*)gp,
                (__attribute__((address_space(3))) unsigned*)lp, 16, 0, 0);
        }
    }

    // zero-write base: 16 lanes span 64 cols (256-B segments), 4 row-groups
    float* zbase = out + (size_t)b * Mdim * Mdim
                 + (size_t)(row0 + (tid >> 4)) * Mdim + cb + (tid & 15) * 4;

    #pragma unroll 1
    for (int ch = 0; ch < 16; ++ch) {
        int cur = ch & 1;
        // barrier: (a) drains this wave's DMA for chunk ch (issued a full
        // compute-phase ago, except ch=0) + old zero-stores; (b) closes all
        // waves' reads of buf[1-cur] from chunk ch-1.
        __syncthreads();
        if (ch + 1 < 16) {   // DMA chunk ch+1 into the buffer just released
            int ncol = cb + (ch + 1) * 64;
            #pragma unroll
            for (int i = 0; i < 4; ++i) {
                const void* gp = xb + (size_t)(ncol + w*16 + i*4 + (lane >> 4)) * FD + (lane & 15) * 8;
                void* lp = (char*)&Bbuf[1 - cur][(w*16 + i*4) * 128];
                __builtin_amdgcn_global_load_lds(
                    (const __attribute__((address_space(1))) unsigned*)gp,
                    (__attribute__((address_space(3))) unsigned*)lp, 16, 0, 0);
            }
        }

        // zero-write this chunk's 128x64 output slice (in flight during MFMA)
        {
            float4 z = make_float4(0.f, 0.f, 0.f, 0.f);
            #pragma unroll
            for (int t = 0; t < 8; ++t)
                *(float4*)(zbase + (size_t)t * 16 * Mdim) = z;
            zbase += 64;
        }

        int col0 = cb + ch * 64;
        f32x4 acc[2][4];
        #pragma unroll
        for (int rs = 0; rs < 2; ++rs)
            #pragma unroll
            for (int ct = 0; ct < 4; ++ct)
                acc[rs][ct] = (f32x4){0.f, 0.f, 0.f, 0.f};

        const unsigned short* Bld = Bbuf[cur];
        #pragma unroll
        for (int s = 0; s < 4; ++s) {
            short8 bfr[4];
            int p = ((s << 2) + q) ^ c;
            #pragma unroll
            for (int ct = 0; ct < 4; ++ct)
                bfr[ct] = *(const short8*)(Bld + (size_t)(ct*16 + c) * 128 + p * 8);
            #pragma unroll
            for (int ct = 0; ct < 4; ++ct) {
                acc[0][ct] = __builtin_amdgcn_mfma_f32_16x16x32_bf16(afr[0][s], bfr[ct], acc[0][ct], 0, 0, 0);
                acc[1][ct] = __builtin_amdgcn_mfma_f32_16x16x32_bf16(afr[1][s], bfr[ct], acc[1][ct], 0, 0, 0);
            }
        }

        // scan on packed keys (diag competes; dropped by index at select)
        int nbase = col0 + c;
        #pragma unroll
        for (int rs = 0; rs < 2; ++rs)
            #pragma unroll
            for (int i = 0; i < 4; ++i) {
                int rr = rs*4 + i;
                unsigned k0 = pkey(acc[rs][0][i], nbase);
                unsigned k1 = pkey(acc[rs][1][i], nbase + 16);
                unsigned k2 = pkey(acc[rs][2][i], nbase + 32);
                unsigned k3 = pkey(acc[rs][3][i], nbase + 48);
                unsigned mx = max(max(k0, k1), max(k2, k3));
                if (mx > tvp[rr][2]) {
                    ins3p(k0, tvp[rr]);
                    ins3p(k1, tvp[rr]);
                    ins3p(k2, tvp[rr]);
                    ins3p(k3, tvp[rr]);
                }
            }
    }

    // ---- cross-lane merge: per-wave scratch reuses the B buffers ----
    __syncthreads();   // all waves done reading both buffers
    unsigned* mb = (unsigned*)&Bbuf[0][0] + w * (32 * 49);   // 4 x 6272 B = 25 KB
    #pragma unroll
    for (int rs = 0; rs < 2; ++rs)
        #pragma unroll
        for (int i = 0; i < 4; ++i) {
            int r = rs*16 + q*4 + i;
            #pragma unroll
            for (int j = 0; j < 3; ++j)
                mb[r*49 + c*3 + j] = tvp[rs*4 + i][j];
        }
    __syncthreads();
    if (lane < 32) {
        unsigned bv[8];
        #pragma unroll
        for (int s = 0; s < 8; ++s) bv[s] = 0;
        for (int s2 = 0; s2 < 48; ++s2)
            ins8p(mb[lane*49 + s2], bv);
        unsigned* pp = pools + ((size_t)b * Mdim + row0 + w*32 + lane) * 16 + hf * 8;
        #pragma unroll
        for (int s = 0; s < 8; ++s) pp[s] = bv[s];
    }
}

// ---------- Kernel 3: merge halves + fp64 refine + exact top-2 + atomic scatter ----------
__global__ void select_kernel(const float* __restrict__ x,
                              const double* __restrict__ nrm_d,
                              const unsigned* __restrict__ pools,
                              float* __restrict__ out) {
    __shared__ unsigned keys[32][8];
    __shared__ double   fval[32][9];
    int tid = threadIdx.x;
    int r = tid >> 3, s = tid & 7;
    int rowg = blockIdx.x * 32 + r;
    int b = rowg >> 11, m = rowg & (Mdim - 1);

    if (s == 0) {
        unsigned bv[8];
        #pragma unroll
        for (int i = 0; i < 8; ++i) bv[i] = 0;
        const unsigned* pp = pools + (size_t)rowg * 16;
        #pragma unroll
        for (int i = 0; i < 16; ++i) ins8p(pp[i], bv);
        #pragma unroll
        for (int i = 0; i < 8; ++i) keys[r][i] = bv[i];
    }
    __syncthreads();

    {
        int n = (int)(keys[r][s] & 2047u);
        const float* xf = x + (size_t)b * Mdim * FD;
        const double* nb = nrm_d + (size_t)b * Mdim;
        const f32x4* pm = (const f32x4*)(xf + (size_t)m * FD);
        const f32x4* pn = (const f32x4*)(xf + (size_t)n * FD);
        double a0 = 0.0, a1 = 0.0;
        #pragma unroll 4
        for (int k4 = 0; k4 < FD/4; k4 += 2) {
            f32x4 u0 = pm[k4],   vv0 = pn[k4];
            f32x4 u1 = pm[k4+1], vv1 = pn[k4+1];
            a0 = fma((double)u0[0], (double)vv0[0], a0);
            a0 = fma((double)u0[1], (double)vv0[1], a0);
            a0 = fma((double)u0[2], (double)vv0[2], a0);
            a0 = fma((double)u0[3], (double)vv0[3], a0);
            a1 = fma((double)u1[0], (double)vv1[0], a1);
            a1 = fma((double)u1[1], (double)vv1[1], a1);
            a1 = fma((double)u1[2], (double)vv1[2], a1);
            a1 = fma((double)u1[3], (double)vv1[3], a1);
        }
        fval[r][s] = (a0 + a1) / (nb[m] * nb[n]);
    }
    __syncthreads();

    if (s == 0) {
        double bv1 = -1e300, bv2 = -1e300; int bi1 = -1, bi2 = -1;
        #pragma unroll
        for (int cc = 0; cc < 8; ++cc) {
            double v = fval[r][cc];
            int    n = (int)(keys[r][cc] & 2047u);
            if (n == m) continue;           // drop self-similarity (diag)
            if (bi1 < 0 || v > bv1 || (v == bv1 && n < bi1)) {
                bv2 = bv1; bi2 = bi1; bv1 = v; bi1 = n;
            } else if (bi2 < 0 || v > bv2 || (v == bv2 && n < bi2)) {
                bv2 = v; bi2 = n;
            }
        }
        float* ob = out + (size_t)b * Mdim * Mdim;
        // reference top_k competes against the zeroed diagonal (value 0):
        // val1 always scatters; val2 only if it beats the diagonal zero.
        float h1 = (float)(0.5 * bv1);
        atomicAdd(ob + (size_t)m * Mdim + bi1, h1);
        atomicAdd(ob + (size_t)bi1 * Mdim + m, h1);
        if (bv2 > 0.0) {
            float h2 = (float)(0.5 * bv2);
            atomicAdd(ob + (size_t)m * Mdim + bi2, h2);
            atomicAdd(ob + (size_t)bi2 * Mdim + m, h2);
        }
    }
}

extern "C" void kernel_launch(void* const* d_in, const int* in_sizes, int n_in,
                              void* d_out, int out_size, void* d_ws, size_t ws_size,
                              hipStream_t stream) {
    const float* x = (const float*)d_in[0];
    float* out = (float*)d_out;
    int Bn = in_sizes[0] / (Mdim * FD);   // 16

    char* ws = (char*)d_ws;
    double*         nrm_d = (double*)ws;                          // 256 KB
    unsigned short* xnb   = (unsigned short*)(ws + 262144);       // 8 MB
    unsigned*       pools = (unsigned*)(ws + 262144 + 8388608);   // 2 MB

    prep_kernel<<<Bn * Mdim / 4, 256, 0, stream>>>(x, nrm_d, xnb);
    gemm_kernel<<<Bn * 32, 256, 0, stream>>>(xnb, pools, out);      // 512 blocks
    select_kernel<<<Bn * Mdim / 32, 256, 0, stream>>>(x, nrm_d, pools, out);
}